// Round 6
// baseline (453.989 us; speedup 1.0000x reference)
//
#include <hip/hip_runtime.h>
#include <hip/hip_bf16.h>

#define B_ 2
#define T_ 2048
#define C_ 2048
#define H_ 16
#define KH_ 4
#define D_ 128

typedef unsigned short ushort_t;
typedef __attribute__((ext_vector_type(8))) short short8;
typedef __attribute__((ext_vector_type(4))) float f32x4;

#define RSQRT_D 0.08838834764831845f
#define L2E 1.4426950408889634f
// Q pre-scale: 1/sqrt(D) * log2(e)  ->  QK^T lands in log2 units, softmax is pure exp2
#define QSCALE (0.08838834764831845f * 1.4426950408889634f)

__device__ __forceinline__ ushort_t f2b(float f) {
  union { float f; unsigned u; } v; v.f = f;
  unsigned r = v.u + 0x7fffu + ((v.u >> 16) & 1u);
  return (ushort_t)(r >> 16);
}
__device__ __forceinline__ float b2f(ushort_t u) {
  union { unsigned u; float f; } v; v.u = ((unsigned)u) << 16;
  return v.f;
}

__device__ __forceinline__ f32x4 mfma16(short8 a, short8 b, f32x4 c) {
  return __builtin_amdgcn_mfma_f32_16x16x32_bf16(a, b, c, 0, 0, 0);
}

__device__ __forceinline__ void async16(const void* g, void* l) {
  __builtin_amdgcn_global_load_lds(
      (const __attribute__((address_space(1))) void*)g,
      (__attribute__((address_space(3))) void*)l, 16, 0, 0);
}

// packed f32x2 -> bf16x2 (RTNE); dst.lo = bf16(lo), dst.hi = bf16(hi)
__device__ __forceinline__ unsigned cvtpk(float lo, float hi) {
  unsigned r;
  asm volatile("v_cvt_pk_bf16_f32 %0, %1, %2" : "=v"(r) : "v"(lo), "v"(hi));
  return r;
}

// ---------------- small prep kernels ----------------

__global__ void convert_f32_bf16(const float* __restrict__ in, ushort_t* __restrict__ out, int n4) {
  int i = blockIdx.x * blockDim.x + threadIdx.x;
  if (i >= n4) return;
  float4 v = ((const float4*)in)[i];
  ushort4 o;
  o.x = f2b(v.x); o.y = f2b(v.y); o.z = f2b(v.z); o.w = f2b(v.w);
  ((ushort4*)out)[i] = o;
}

// out[c][r] = bf16(in[r][c]);  in: R x C f32, out: C x R bf16
__global__ void transpose_to_bf16(const float* __restrict__ in, ushort_t* __restrict__ out, int R, int C) {
  __shared__ float tile[32][33];
  int c0 = blockIdx.x * 32, r0 = blockIdx.y * 32;
  int tx = threadIdx.x, ty = threadIdx.y;
#pragma unroll
  for (int i = 0; i < 4; i++) {
    int r = ty + i * 8;
    tile[r][tx] = in[(size_t)(r0 + r) * C + c0 + tx];
  }
  __syncthreads();
#pragma unroll
  for (int i = 0; i < 4; i++) {
    int r = ty + i * 8;
    out[(size_t)(c0 + r) * R + r0 + tx] = f2b(tile[tx][r]);
  }
}

// cos/sin table: tab[t*64+d] = (cos(t*omega[d]), sin(t*omega[d]))
__global__ void rope_tab_k(const float* __restrict__ omega, float2* __restrict__ tab) {
  int idx = blockIdx.x * blockDim.x + threadIdx.x;  // 2048*64
  int d = idx & 63;
  int t = idx >> 6;
  float ang = (float)t * omega[d];
  tab[idx] = make_float2(cosf(ang), sinf(ang));
}

// QKVraw [b*T+t][3072]: cols 0..2047 = q -> rope (pre-scaled by QSCALE) -> Qb [(b*16+h)*T + t][d]
__global__ void rope_q_k(const ushort_t* __restrict__ QKVraw, const float2* __restrict__ tab,
                         ushort_t* __restrict__ Qb) {
  int idx = blockIdx.x * blockDim.x + threadIdx.x;  // B*T*H*64 = 4194304
  int d = idx & 63;
  int h = (idx >> 6) & 15;
  int t = (idx >> 10) & 2047;
  int b = idx >> 21;
  size_t in_off = (size_t)(b * 2048 + t) * 3072 + h * 128 + d;
  float x1 = b2f(QKVraw[in_off]);
  float x2 = b2f(QKVraw[in_off + 64]);
  float2 cs = tab[t * 64 + d];
  size_t out_off = ((size_t)(b * 16 + h) * 2048 + t) * 128 + d;
  Qb[out_off] = f2b((x1 * cs.x - x2 * cs.y) * QSCALE);
  Qb[out_off + 64] = f2b((x1 * cs.y + x2 * cs.x) * QSCALE);
}

// QKVraw cols 2048..2559 = k -> rope -> Kb [(b*4+kh)*T + t][d]
__global__ void rope_k_k(const ushort_t* __restrict__ QKVraw, const float2* __restrict__ tab,
                         ushort_t* __restrict__ Kb) {
  int idx = blockIdx.x * blockDim.x + threadIdx.x;  // B*T*KH*64 = 1048576
  int d = idx & 63;
  int kh = (idx >> 6) & 3;
  int t = (idx >> 8) & 2047;
  int b = idx >> 19;
  size_t in_off = (size_t)(b * 2048 + t) * 3072 + 2048 + kh * 128 + d;
  float x1 = b2f(QKVraw[in_off]);
  float x2 = b2f(QKVraw[in_off + 64]);
  float2 cs = tab[t * 64 + d];
  size_t out_off = ((size_t)(b * 4 + kh) * 2048 + t) * 128 + d;
  Kb[out_off] = f2b(x1 * cs.x - x2 * cs.y);
  Kb[out_off + 64] = f2b(x1 * cs.y + x2 * cs.x);
}

// V fragment pre-pack: Vf short8 index = (((z*32+tile)*2+hv)*8+n)*64 + lane
// element j = V[b][t = tile*64 + kl][kh][d = n*16 + (lane&15)]
// kl = (hv*2 + ((j>>1)>>1))*16 + (lane>>4)*4 + 2*((j>>1)&1) + (j&1)
__global__ void v_frag_k(const ushort_t* __restrict__ QKVraw, ushort_t* __restrict__ Vf) {
  int idx = blockIdx.x * blockDim.x + threadIdx.x;  // 262144 short8 units
  int lane = idx & 63;
  int n = (idx >> 6) & 7;
  int hv = (idx >> 9) & 1;
  int tile = (idx >> 10) & 31;
  int z = idx >> 15;  // b*4+kh
  int b = z >> 2, kh = z & 3;
  int lr = lane & 15, lc = lane >> 4;
  int d = n * 16 + lr;
  union { ushort_t u[8]; short8 v; } out;
#pragma unroll
  for (int j = 0; j < 8; j++) {
    int tw = j >> 1, par = j & 1;
    int kl = (hv * 2 + (tw >> 1)) * 16 + lc * 4 + 2 * (tw & 1) + par;
    int t = tile * 64 + kl;
    out.u[j] = QKVraw[(size_t)(b * 2048 + t) * 3072 + 2560 + kh * 128 + d];
  }
  *(short8*)(Vf + (size_t)idx * 8) = out.v;
}

// ---------------- GEMM: C[M][N] = A[M][K] @ Bt[N][K]^T  (bf16 in, f32 acc) ----------------
// 2-phase dbuf with COUNTED vmcnt (T4): raw s_barrier, vmcnt(4) keeps the 4
// prefetch loads in flight across the MFMA phase; vmcnt(0) only on the peeled
// last tile. FIFO vmcnt semantics guarantee tile-t's 4 loads are done.

__device__ __forceinline__ void store_out(float* C, size_t idx, float v) { C[idx] = v; }
__device__ __forceinline__ void store_out(ushort_t* C, size_t idx, float v) { C[idx] = f2b(v); }

template <typename OUT_T>
__global__ __launch_bounds__(256) void gemm_bt(const ushort_t* __restrict__ A,
                                               const ushort_t* __restrict__ Bt,
                                               OUT_T* __restrict__ C,
                                               int M, int N, int K) {
  __shared__ __attribute__((aligned(16))) ushort_t As[2][128 * 32];
  __shared__ __attribute__((aligned(16))) ushort_t Bs[2][128 * 32];
  const int tid = threadIdx.x;
  const int lane = tid & 63;
  const int w = tid >> 6;
  const int bm = blockIdx.y, bn = blockIdx.x;
  const int lr = lane & 15, lc = lane >> 4;
  const int wr = (w >> 1) * 64, wc = (w & 1) * 64;
  const ushort_t* Ab = A + (size_t)bm * 128 * K;
  const ushort_t* Bb = Bt + (size_t)bn * 128 * K;
  const int srow = tid >> 2;
  const int scol = (tid & 3) * 8;
  f32x4 acc[4][4];
#pragma unroll
  for (int i = 0; i < 4; i++)
#pragma unroll
    for (int j = 0; j < 4; j++) acc[i][j] = (f32x4)(0.0f);

  // prologue: stage tile 0 into buf 0 (4 vmem ops per wave)
  async16(Ab + (size_t)srow * K + scol, &As[0][0] + srow * 32 + scol);
  async16(Ab + (size_t)(srow + 64) * K + scol, &As[0][0] + (srow + 64) * 32 + scol);
  async16(Bb + (size_t)srow * K + scol, &Bs[0][0] + srow * 32 + scol);
  async16(Bb + (size_t)(srow + 64) * K + scol, &Bs[0][0] + (srow + 64) * 32 + scol);

  const int nt = K >> 5;
#pragma unroll 2
  for (int t = 0; t < nt - 1; t++) {
    const int cur = t & 1;
    // issue prefetch of tile t+1 into the other buffer (4 vmem ops)
    {
      const int k1 = (t + 1) << 5;
      ushort_t* Ad = &As[cur ^ 1][0];
      ushort_t* Bd = &Bs[cur ^ 1][0];
      async16(Ab + (size_t)srow * K + k1 + scol, Ad + srow * 32 + scol);
      async16(Ab + (size_t)(srow + 64) * K + k1 + scol, Ad + (srow + 64) * 32 + scol);
      async16(Bb + (size_t)srow * K + k1 + scol, Bd + srow * 32 + scol);
      async16(Bb + (size_t)(srow + 64) * K + k1 + scol, Bd + (srow + 64) * 32 + scol);
    }
    // wait tile t's 4 loads (oldest); let t+1's 4 stay in flight
    asm volatile("s_waitcnt vmcnt(4)" ::: "memory");
    __builtin_amdgcn_s_barrier();
    __builtin_amdgcn_sched_barrier(0);
    const ushort_t* Al = &As[cur][0];
    const ushort_t* Bl = &Bs[cur][0];
    short8 af[4], bf[4];
#pragma unroll
    for (int mi = 0; mi < 4; mi++)
      af[mi] = *(const short8*)(Al + (wr + mi * 16 + lr) * 32 + lc * 8);
#pragma unroll
    for (int ni = 0; ni < 4; ni++)
      bf[ni] = *(const short8*)(Bl + (wc + ni * 16 + lr) * 32 + lc * 8);
#pragma unroll
    for (int mi = 0; mi < 4; mi++)
#pragma unroll
      for (int ni = 0; ni < 4; ni++)
        acc[mi][ni] = mfma16(af[mi], bf[ni], acc[mi][ni]);
    asm volatile("" ::: "memory");
    __builtin_amdgcn_s_barrier();  // all waves done reading buf[cur] before t+2 overwrites
    asm volatile("" ::: "memory");
  }
  // peeled last tile: drain, then compute
  {
    const int cur = (nt - 1) & 1;
    asm volatile("s_waitcnt vmcnt(0)" ::: "memory");
    __builtin_amdgcn_s_barrier();
    __builtin_amdgcn_sched_barrier(0);
    const ushort_t* Al = &As[cur][0];
    const ushort_t* Bl = &Bs[cur][0];
    short8 af[4], bf[4];
#pragma unroll
    for (int mi = 0; mi < 4; mi++)
      af[mi] = *(const short8*)(Al + (wr + mi * 16 + lr) * 32 + lc * 8);
#pragma unroll
    for (int ni = 0; ni < 4; ni++)
      bf[ni] = *(const short8*)(Bl + (wc + ni * 16 + lr) * 32 + lc * 8);
#pragma unroll
    for (int mi = 0; mi < 4; mi++)
#pragma unroll
      for (int ni = 0; ni < 4; ni++)
        acc[mi][ni] = mfma16(af[mi], bf[ni], acc[mi][ni]);
  }
#pragma unroll
  for (int mi = 0; mi < 4; mi++) {
#pragma unroll
    for (int ni = 0; ni < 4; ni++) {
      int row = bm * 128 + wr + mi * 16 + lc * 4;
      int col = bn * 128 + wc + ni * 16 + lr;
#pragma unroll
      for (int r = 0; r < 4; r++)
        store_out(C, (size_t)(row + r) * N + col, acc[mi][ni][r]);
    }
  }
}

// ---------------- flash attention (causal GQA) ----------------
// 256 threads = 4 waves; wave w owns 16 q-rows (q0w = qc*64 + w*16).
// One 64-row q-chunk per block (1024 blocks, heavy-first) -> 4 blocks/CU.
// Swapped QK^T (mfma(K,Q)): lane holds S row q = q0w+lr, k = kv0+kj*16+lc*4+r.
// Q pre-scaled by QSCALE (=1/sqrt(D)*log2e) -> softmax is pure exp2.
// Defer-max (thr 8 log2-units => P<=2^8). K staged in LDS (KVBLK=64, dbuf).
__global__ __launch_bounds__(256, 4) void attn_k(const ushort_t* __restrict__ Qb,
                                                 const ushort_t* __restrict__ Kb,
                                                 const ushort_t* __restrict__ Vf,
                                                 ushort_t* __restrict__ Yb) {
  __shared__ __attribute__((aligned(16))) ushort_t Ks[2][64 * 128];  // 32 KB
  const int tid = threadIdx.x;
  const int lane = tid & 63;
  const int w = tid >> 6;
  const int lr = lane & 15, lc = lane >> 4;
  const int h = blockIdx.y;
  const int b = blockIdx.z;
  const int kh = h >> 2;
  const int qc = 31 - blockIdx.x;   // heavy chunks dispatched first
  const int q0w = qc * 64 + w * 16;
  const int q = q0w + lr;           // this lane's q-row

  const ushort_t* Qp = Qb + (size_t)(b * 16 + h) * T_ * D_;
  const ushort_t* Kp = Kb + (size_t)(b * 4 + kh) * T_ * D_;
  const ushort_t* Vfb = Vf + (size_t)(b * 4 + kh) * 262144;

  const int st_row = tid >> 4;   // 0..15, +i*16
  const int st_slot = tid & 15;

  short8 qf[4];
#pragma unroll
  for (int c = 0; c < 4; c++)
    qf[c] = *(const short8*)(Qp + (size_t)(q0w + lr) * D_ + c * 32 + lc * 8);

  f32x4 o[8];
#pragma unroll
  for (int n = 0; n < 8; n++) o[n] = (f32x4)(0.0f);
  float m = -1e30f, l = 0.0f;

  const int nt = qc + 1;

  // stage tile 0 into buffer 0
#pragma unroll
  for (int i = 0; i < 4; i++) {
    int row = i * 16 + st_row;
    async16(Kp + (size_t)row * D_ + (((st_slot - row) & 15) * 8),
            &Ks[0][0] + row * 128 + st_slot * 8);
  }

#pragma unroll 1
  for (int ti = 0; ti < nt; ti++) {
    __syncthreads();  // K[ti] resident (vmcnt drained); buffers safe
    const int kv0 = ti * 64;
    if (ti + 1 < nt) {
      const ushort_t* Kn = Kp + (size_t)(kv0 + 64) * D_;
      ushort_t* dst = &Ks[(ti + 1) & 1][0];
#pragma unroll
      for (int i = 0; i < 4; i++) {
        int row = i * 16 + st_row;
        async16(Kn + (size_t)row * D_ + (((st_slot - row) & 15) * 8),
                dst + row * 128 + st_slot * 8);
      }
    }
    const ushort_t* Kl = &Ks[ti & 1][0];
    // V half 0 — early issue, hidden under QK
    const ushort_t* Vt0 = Vfb + (size_t)(ti * 2) * 4096;
    short8 vr0[8];
#pragma unroll
    for (int n = 0; n < 8; n++)
      vr0[n] = *(const short8*)(Vt0 + n * 512 + lane * 8);
    // QK^T swapped: s[kj] lane layout: q = q0w+lr (col), k = kv0+kj*16+lc*4+r (row)
    f32x4 s[4];
#pragma unroll
    for (int kj = 0; kj < 4; kj++) s[kj] = (f32x4)(0.0f);
    __builtin_amdgcn_s_setprio(1);
#pragma unroll
    for (int c = 0; c < 4; c++) {
      short8 kf[4];
#pragma unroll
      for (int kj = 0; kj < 4; kj++)
        kf[kj] = *(const short8*)(Kl + (kj * 16 + lr) * 128 + (((c * 4 + lc + lr) & 15) * 8));
#pragma unroll
      for (int kj = 0; kj < 4; kj++)
        s[kj] = mfma16(kf[kj], qf[c], s[kj]);
    }
    __builtin_amdgcn_s_setprio(0);
    // V half 1 — hidden under softmax
    const ushort_t* Vt1 = Vfb + (size_t)(ti * 2 + 1) * 4096;
    short8 vr1[8];
#pragma unroll
    for (int n = 0; n < 8; n++)
      vr1[n] = *(const short8*)(Vt1 + n * 512 + lane * 8);
    // in-register softmax (per-lane row q), all in log2 units
    float pv[16];
    float mx = -1e30f;
    if (kv0 + 63 > q0w) {
#pragma unroll
      for (int kj = 0; kj < 4; kj++)
#pragma unroll
        for (int r = 0; r < 4; r++) {
          float a = s[kj][r];
          if (kv0 + kj * 16 + lc * 4 + r > q) a = -1e30f;
          pv[kj * 4 + r] = a;
          mx = fmaxf(mx, a);
        }
    } else {
#pragma unroll
      for (int kj = 0; kj < 4; kj++)
#pragma unroll
        for (int r = 0; r < 4; r++) {
          float a = s[kj][r];
          pv[kj * 4 + r] = a;
          mx = fmaxf(mx, a);
        }
    }
    mx = fmaxf(mx, __shfl_xor(mx, 16));
    mx = fmaxf(mx, __shfl_xor(mx, 32));
    // defer-max: rescale only when some row grew > 8 (log2) => P <= 2^8
    const bool need = __any(mx > m + 8.0f);
    const float mn = need ? fmaxf(m, mx) : m;
    float rs = 0.0f;
#pragma unroll
    for (int i = 0; i < 16; i++) {
      pv[i] = exp2f(pv[i] - mn);
      rs += pv[i];
    }
    rs += __shfl_xor(rs, 16);
    rs += __shfl_xor(rs, 32);
    // pack P to bf16 A-frags (in-lane; layout matches Vf's sigma)
    unsigned Wd[8];
#pragma unroll
    for (int kj = 0; kj < 4; kj++) {
      Wd[kj * 2] = cvtpk(pv[kj * 4], pv[kj * 4 + 1]);
      Wd[kj * 2 + 1] = cvtpk(pv[kj * 4 + 2], pv[kj * 4 + 3]);
    }
    union { unsigned u[4]; short8 v; } pa0, pa1;
#pragma unroll
    for (int t = 0; t < 4; t++) { pa0.u[t] = Wd[t]; pa1.u[t] = Wd[4 + t]; }
    if (need) {
      float al = exp2f(m - mn);
      m = mn;
      l = l * al + rs;
      float alT[4];
#pragma unroll
      for (int r = 0; r < 4; r++)
        alT[r] = __shfl(al, (lane & 48) | (lc * 4 + r));
#pragma unroll
      for (int n = 0; n < 8; n++)
#pragma unroll
        for (int r = 0; r < 4; r++) o[n][r] *= alT[r];
    } else {
      l += rs;
    }
    __builtin_amdgcn_s_setprio(1);
#pragma unroll
    for (int n = 0; n < 8; n++) o[n] = mfma16(pa0.v, vr0[n], o[n]);
#pragma unroll
    for (int n = 0; n < 8; n++) o[n] = mfma16(pa1.v, vr1[n], o[n]);
    __builtin_amdgcn_s_setprio(0);
  }
  // epilogue: o rows are q = q0w + lc*4 + r; l lives at lane q = q0w + lr
  float inv = 1.0f / l;
  float invT[4];
#pragma unroll
  for (int r = 0; r < 4; r++)
    invT[r] = __shfl(inv, (lane & 48) | (lc * 4 + r));
#pragma unroll
  for (int n = 0; n < 8; n++)
#pragma unroll
    for (int r = 0; r < 4; r++) {
      int qo = q0w + lc * 4 + r;
      int d = n * 16 + lr;
      Yb[(size_t)(b * T_ + qo) * 2048 + h * 128 + d] = f2b(o[n][r] * invT[r]);
    }
}

// ---------------- launch ----------------

extern "C" void kernel_launch(void* const* d_in, const int* in_sizes, int n_in,
                              void* d_out, int out_size, void* d_ws, size_t ws_size,
                              hipStream_t stream) {
  (void)in_sizes; (void)n_in; (void)out_size; (void)ws_size;
  const float* x = (const float*)d_in[0];
  const float* wq = (const float*)d_in[1];
  const float* wkv = (const float*)d_in[2];
  const float* wproj = (const float*)d_in[3];
  const float* omega = (const float*)d_in[4];
  float* out = (float*)d_out;
  char* ws = (char*)d_ws;

  ushort_t* xb     = (ushort_t*)(ws + 0);          // 4096x2048 bf16 = 16.8MB
  ushort_t* wqkvT  = (ushort_t*)(ws + 16777216);   // [3072][2048] bf16 (wqT then wkvT)
  ushort_t* wkvT   = (ushort_t*)(ws + 25165824);   // tail of wqkvT
  ushort_t* wprojT = (ushort_t*)(ws + 29360128);   // 2048x2048 bf16
  ushort_t* QKVraw = (ushort_t*)(ws + 37748736);   // 4096x3072 bf16 = 25.2MB
  ushort_t* Qb     = (ushort_t*)(ws + 62914560);   // [b][h][t][d] bf16
  ushort_t* Kb     = (ushort_t*)(ws + 79691776);   // [b][kh][t][d] bf16
  ushort_t* Vf     = (ushort_t*)(ws + 83886080);   // V fragment-packed, 4MB
  ushort_t* Yb     = (ushort_t*)(ws + 88080384);   // 4096x2048 bf16
  float2*   tab    = (float2*)(ws + 104857600);    // 2048x64 float2 = 1MB

  convert_f32_bf16<<<8192, 256, 0, stream>>>(x, xb, 2097152);
  transpose_to_bf16<<<dim3(64, 64), dim3(32, 8), 0, stream>>>(wq, wqkvT, 2048, 2048);
  transpose_to_bf16<<<dim3(32, 64), dim3(32, 8), 0, stream>>>(wkv, wkvT, 2048, 1024);
  transpose_to_bf16<<<dim3(64, 64), dim3(32, 8), 0, stream>>>(wproj, wprojT, 2048, 2048);
  rope_tab_k<<<512, 256, 0, stream>>>(omega, tab);

  // merged QKV projection: [4096,2048] @ [3072,2048]^T -> [4096,3072]
  gemm_bt<<<dim3(24, 32), 256, 0, stream>>>(xb, wqkvT, QKVraw, 4096, 3072, 2048);

  rope_q_k<<<16384, 256, 0, stream>>>(QKVraw, tab, Qb);
  rope_k_k<<<4096, 256, 0, stream>>>(QKVraw, tab, Kb);
  v_frag_k<<<1024, 256, 0, stream>>>(QKVraw, Vf);

  attn_k<<<dim3(32, 16, 2), 256, 0, stream>>>(Qb, Kb, Vf, Yb);

  gemm_bt<<<dim3(16, 32), 256, 0, stream>>>(Yb, wprojT, out, 4096, 2048, 2048);
}

// Round 7
// 256.495 us; speedup vs baseline: 1.7700x; 1.7700x over previous
//
#include <hip/hip_runtime.h>
#include <hip/hip_bf16.h>

#define B_ 2
#define T_ 2048
#define C_ 2048
#define H_ 16
#define KH_ 4
#define D_ 128

typedef unsigned short ushort_t;
typedef __attribute__((ext_vector_type(8))) short short8;
typedef __attribute__((ext_vector_type(4))) float f32x4;

#define RSQRT_D 0.08838834764831845f
#define L2E 1.4426950408889634f
// Q pre-scale: 1/sqrt(D) * log2(e)  ->  QK^T lands in log2 units, softmax is pure exp2
#define QSCALE (0.08838834764831845f * 1.4426950408889634f)

__device__ __forceinline__ ushort_t f2b(float f) {
  union { float f; unsigned u; } v; v.f = f;
  unsigned r = v.u + 0x7fffu + ((v.u >> 16) & 1u);
  return (ushort_t)(r >> 16);
}
__device__ __forceinline__ float b2f(ushort_t u) {
  union { unsigned u; float f; } v; v.u = ((unsigned)u) << 16;
  return v.f;
}

__device__ __forceinline__ f32x4 mfma16(short8 a, short8 b, f32x4 c) {
  return __builtin_amdgcn_mfma_f32_16x16x32_bf16(a, b, c, 0, 0, 0);
}

__device__ __forceinline__ void async16(const void* g, void* l) {
  __builtin_amdgcn_global_load_lds(
      (const __attribute__((address_space(1))) void*)g,
      (__attribute__((address_space(3))) void*)l, 16, 0, 0);
}

// packed f32x2 -> bf16x2 (RTNE); dst.lo = bf16(lo), dst.hi = bf16(hi)
__device__ __forceinline__ unsigned cvtpk(float lo, float hi) {
  unsigned r;
  asm volatile("v_cvt_pk_bf16_f32 %0, %1, %2" : "=v"(r) : "v"(lo), "v"(hi));
  return r;
}

// ---------------- small prep kernels ----------------

__global__ void convert_f32_bf16(const float* __restrict__ in, ushort_t* __restrict__ out, int n4) {
  int i = blockIdx.x * blockDim.x + threadIdx.x;
  if (i >= n4) return;
  float4 v = ((const float4*)in)[i];
  ushort4 o;
  o.x = f2b(v.x); o.y = f2b(v.y); o.z = f2b(v.z); o.w = f2b(v.w);
  ((ushort4*)out)[i] = o;
}

// out[c][r] = bf16(in[r][c]);  in: R x C f32, out: C x R bf16
__global__ void transpose_to_bf16(const float* __restrict__ in, ushort_t* __restrict__ out, int R, int C) {
  __shared__ float tile[32][33];
  int c0 = blockIdx.x * 32, r0 = blockIdx.y * 32;
  int tx = threadIdx.x, ty = threadIdx.y;
#pragma unroll
  for (int i = 0; i < 4; i++) {
    int r = ty + i * 8;
    tile[r][tx] = in[(size_t)(r0 + r) * C + c0 + tx];
  }
  __syncthreads();
#pragma unroll
  for (int i = 0; i < 4; i++) {
    int r = ty + i * 8;
    out[(size_t)(c0 + r) * R + r0 + tx] = f2b(tile[tx][r]);
  }
}

// cos/sin table: tab[t*64+d] = (cos(t*omega[d]), sin(t*omega[d]))
__global__ void rope_tab_k(const float* __restrict__ omega, float2* __restrict__ tab) {
  int idx = blockIdx.x * blockDim.x + threadIdx.x;  // 2048*64
  int d = idx & 63;
  int t = idx >> 6;
  float ang = (float)t * omega[d];
  tab[idx] = make_float2(cosf(ang), sinf(ang));
}

// QKVraw [b*T+t][3072]: cols 0..2047 = q -> rope (pre-scaled by QSCALE) -> Qb [(b*16+h)*T + t][d]
__global__ void rope_q_k(const ushort_t* __restrict__ QKVraw, const float2* __restrict__ tab,
                         ushort_t* __restrict__ Qb) {
  int idx = blockIdx.x * blockDim.x + threadIdx.x;  // B*T*H*64 = 4194304
  int d = idx & 63;
  int h = (idx >> 6) & 15;
  int t = (idx >> 10) & 2047;
  int b = idx >> 21;
  size_t in_off = (size_t)(b * 2048 + t) * 3072 + h * 128 + d;
  float x1 = b2f(QKVraw[in_off]);
  float x2 = b2f(QKVraw[in_off + 64]);
  float2 cs = tab[t * 64 + d];
  size_t out_off = ((size_t)(b * 16 + h) * 2048 + t) * 128 + d;
  Qb[out_off] = f2b((x1 * cs.x - x2 * cs.y) * QSCALE);
  Qb[out_off + 64] = f2b((x1 * cs.y + x2 * cs.x) * QSCALE);
}

// QKVraw cols 2048..2559 = k -> rope -> Kb [(b*4+kh)*T + t][d]
__global__ void rope_k_k(const ushort_t* __restrict__ QKVraw, const float2* __restrict__ tab,
                         ushort_t* __restrict__ Kb) {
  int idx = blockIdx.x * blockDim.x + threadIdx.x;  // B*T*KH*64 = 1048576
  int d = idx & 63;
  int kh = (idx >> 6) & 3;
  int t = (idx >> 8) & 2047;
  int b = idx >> 19;
  size_t in_off = (size_t)(b * 2048 + t) * 3072 + 2048 + kh * 128 + d;
  float x1 = b2f(QKVraw[in_off]);
  float x2 = b2f(QKVraw[in_off + 64]);
  float2 cs = tab[t * 64 + d];
  size_t out_off = ((size_t)(b * 4 + kh) * 2048 + t) * 128 + d;
  Kb[out_off] = f2b(x1 * cs.x - x2 * cs.y);
  Kb[out_off + 64] = f2b(x1 * cs.y + x2 * cs.x);
}

// V fragment pre-pack: Vf short8 index = (((z*32+tile)*2+hv)*8+n)*64 + lane
// element j = V[b][t = tile*64 + kl][kh][d = n*16 + (lane&15)]
// kl = (hv*2 + ((j>>1)>>1))*16 + (lane>>4)*4 + 2*((j>>1)&1) + (j&1)
__global__ void v_frag_k(const ushort_t* __restrict__ QKVraw, ushort_t* __restrict__ Vf) {
  int idx = blockIdx.x * blockDim.x + threadIdx.x;  // 262144 short8 units
  int lane = idx & 63;
  int n = (idx >> 6) & 7;
  int hv = (idx >> 9) & 1;
  int tile = (idx >> 10) & 31;
  int z = idx >> 15;  // b*4+kh
  int b = z >> 2, kh = z & 3;
  int lr = lane & 15, lc = lane >> 4;
  int d = n * 16 + lr;
  union { ushort_t u[8]; short8 v; } out;
#pragma unroll
  for (int j = 0; j < 8; j++) {
    int tw = j >> 1, par = j & 1;
    int kl = (hv * 2 + (tw >> 1)) * 16 + lc * 4 + 2 * (tw & 1) + par;
    int t = tile * 64 + kl;
    out.u[j] = QKVraw[(size_t)(b * 2048 + t) * 3072 + 2560 + kh * 128 + d];
  }
  *(short8*)(Vf + (size_t)idx * 8) = out.v;
}

// ---------------- GEMM: C[M][N] = A[M][K] @ Bt[N][K]^T  (bf16 in, f32 acc) ----------------
// 2-phase dbuf with COUNTED vmcnt (T4): raw s_barrier, vmcnt(4) keeps the 4
// prefetch loads in flight across the MFMA phase; vmcnt(0) only on the peeled
// last tile. FIFO vmcnt semantics guarantee tile-t's 4 loads are done.

__device__ __forceinline__ void store_out(float* C, size_t idx, float v) { C[idx] = v; }
__device__ __forceinline__ void store_out(ushort_t* C, size_t idx, float v) { C[idx] = f2b(v); }

template <typename OUT_T>
__global__ __launch_bounds__(256) void gemm_bt(const ushort_t* __restrict__ A,
                                               const ushort_t* __restrict__ Bt,
                                               OUT_T* __restrict__ C,
                                               int M, int N, int K) {
  __shared__ __attribute__((aligned(16))) ushort_t As[2][128 * 32];
  __shared__ __attribute__((aligned(16))) ushort_t Bs[2][128 * 32];
  const int tid = threadIdx.x;
  const int lane = tid & 63;
  const int w = tid >> 6;
  const int bm = blockIdx.y, bn = blockIdx.x;
  const int lr = lane & 15, lc = lane >> 4;
  const int wr = (w >> 1) * 64, wc = (w & 1) * 64;
  const ushort_t* Ab = A + (size_t)bm * 128 * K;
  const ushort_t* Bb = Bt + (size_t)bn * 128 * K;
  const int srow = tid >> 2;
  const int scol = (tid & 3) * 8;
  f32x4 acc[4][4];
#pragma unroll
  for (int i = 0; i < 4; i++)
#pragma unroll
    for (int j = 0; j < 4; j++) acc[i][j] = (f32x4)(0.0f);

  // prologue: stage tile 0 into buf 0 (4 vmem ops per wave)
  async16(Ab + (size_t)srow * K + scol, &As[0][0] + srow * 32 + scol);
  async16(Ab + (size_t)(srow + 64) * K + scol, &As[0][0] + (srow + 64) * 32 + scol);
  async16(Bb + (size_t)srow * K + scol, &Bs[0][0] + srow * 32 + scol);
  async16(Bb + (size_t)(srow + 64) * K + scol, &Bs[0][0] + (srow + 64) * 32 + scol);

  const int nt = K >> 5;
#pragma unroll 2
  for (int t = 0; t < nt - 1; t++) {
    const int cur = t & 1;
    // issue prefetch of tile t+1 into the other buffer (4 vmem ops)
    {
      const int k1 = (t + 1) << 5;
      ushort_t* Ad = &As[cur ^ 1][0];
      ushort_t* Bd = &Bs[cur ^ 1][0];
      async16(Ab + (size_t)srow * K + k1 + scol, Ad + srow * 32 + scol);
      async16(Ab + (size_t)(srow + 64) * K + k1 + scol, Ad + (srow + 64) * 32 + scol);
      async16(Bb + (size_t)srow * K + k1 + scol, Bd + srow * 32 + scol);
      async16(Bb + (size_t)(srow + 64) * K + k1 + scol, Bd + (srow + 64) * 32 + scol);
    }
    // wait tile t's 4 loads (oldest); let t+1's 4 stay in flight
    asm volatile("s_waitcnt vmcnt(4)" ::: "memory");
    __builtin_amdgcn_s_barrier();
    __builtin_amdgcn_sched_barrier(0);
    const ushort_t* Al = &As[cur][0];
    const ushort_t* Bl = &Bs[cur][0];
    short8 af[4], bf[4];
#pragma unroll
    for (int mi = 0; mi < 4; mi++)
      af[mi] = *(const short8*)(Al + (wr + mi * 16 + lr) * 32 + lc * 8);
#pragma unroll
    for (int ni = 0; ni < 4; ni++)
      bf[ni] = *(const short8*)(Bl + (wc + ni * 16 + lr) * 32 + lc * 8);
#pragma unroll
    for (int mi = 0; mi < 4; mi++)
#pragma unroll
      for (int ni = 0; ni < 4; ni++)
        acc[mi][ni] = mfma16(af[mi], bf[ni], acc[mi][ni]);
    asm volatile("" ::: "memory");
    __builtin_amdgcn_s_barrier();  // all waves done reading buf[cur] before t+2 overwrites
    asm volatile("" ::: "memory");
  }
  // peeled last tile: drain, then compute
  {
    const int cur = (nt - 1) & 1;
    asm volatile("s_waitcnt vmcnt(0)" ::: "memory");
    __builtin_amdgcn_s_barrier();
    __builtin_amdgcn_sched_barrier(0);
    const ushort_t* Al = &As[cur][0];
    const ushort_t* Bl = &Bs[cur][0];
    short8 af[4], bf[4];
#pragma unroll
    for (int mi = 0; mi < 4; mi++)
      af[mi] = *(const short8*)(Al + (wr + mi * 16 + lr) * 32 + lc * 8);
#pragma unroll
    for (int ni = 0; ni < 4; ni++)
      bf[ni] = *(const short8*)(Bl + (wc + ni * 16 + lr) * 32 + lc * 8);
#pragma unroll
    for (int mi = 0; mi < 4; mi++)
#pragma unroll
      for (int ni = 0; ni < 4; ni++)
        acc[mi][ni] = mfma16(af[mi], bf[ni], acc[mi][ni]);
  }
#pragma unroll
  for (int mi = 0; mi < 4; mi++) {
#pragma unroll
    for (int ni = 0; ni < 4; ni++) {
      int row = bm * 128 + wr + mi * 16 + lc * 4;
      int col = bn * 128 + wc + ni * 16 + lr;
#pragma unroll
      for (int r = 0; r < 4; r++)
        store_out(C, (size_t)(row + r) * N + col, acc[mi][ni][r]);
    }
  }
}

// ---------------- flash attention (causal GQA) ----------------
// 256 threads = 4 waves; wave w owns 16 q-rows (q0w = qc*64 + w*16).
// One 64-row q-chunk per block (1024 blocks, heavy-first).
// launch_bounds min-waves kept at 2: requesting 4 clamps VGPR to 64 and spills
// (R6: WRITE_SIZE 390MB, 316us). VGPR 96 + LDS 32KB already allow ~5 blocks/CU.
// Swapped QK^T (mfma(K,Q)): lane holds S row q = q0w+lr, k = kv0+kj*16+lc*4+r.
// Q pre-scaled by QSCALE (=1/sqrt(D)*log2e) -> softmax is pure exp2.
// Defer-max (thr 8 log2-units => P<=2^8). K staged in LDS (KVBLK=64, dbuf).
__global__ __launch_bounds__(256, 2) void attn_k(const ushort_t* __restrict__ Qb,
                                                 const ushort_t* __restrict__ Kb,
                                                 const ushort_t* __restrict__ Vf,
                                                 ushort_t* __restrict__ Yb) {
  __shared__ __attribute__((aligned(16))) ushort_t Ks[2][64 * 128];  // 32 KB
  const int tid = threadIdx.x;
  const int lane = tid & 63;
  const int w = tid >> 6;
  const int lr = lane & 15, lc = lane >> 4;
  const int h = blockIdx.y;
  const int b = blockIdx.z;
  const int kh = h >> 2;
  const int qc = 31 - blockIdx.x;   // heavy chunks dispatched first
  const int q0w = qc * 64 + w * 16;
  const int q = q0w + lr;           // this lane's q-row

  const ushort_t* Qp = Qb + (size_t)(b * 16 + h) * T_ * D_;
  const ushort_t* Kp = Kb + (size_t)(b * 4 + kh) * T_ * D_;
  const ushort_t* Vfb = Vf + (size_t)(b * 4 + kh) * 262144;

  const int st_row = tid >> 4;   // 0..15, +i*16
  const int st_slot = tid & 15;

  short8 qf[4];
#pragma unroll
  for (int c = 0; c < 4; c++)
    qf[c] = *(const short8*)(Qp + (size_t)(q0w + lr) * D_ + c * 32 + lc * 8);

  f32x4 o[8];
#pragma unroll
  for (int n = 0; n < 8; n++) o[n] = (f32x4)(0.0f);
  float m = -1e30f, l = 0.0f;

  const int nt = qc + 1;

  // stage tile 0 into buffer 0
#pragma unroll
  for (int i = 0; i < 4; i++) {
    int row = i * 16 + st_row;
    async16(Kp + (size_t)row * D_ + (((st_slot - row) & 15) * 8),
            &Ks[0][0] + row * 128 + st_slot * 8);
  }

#pragma unroll 1
  for (int ti = 0; ti < nt; ti++) {
    __syncthreads();  // K[ti] resident (vmcnt drained); buffers safe
    const int kv0 = ti * 64;
    if (ti + 1 < nt) {
      const ushort_t* Kn = Kp + (size_t)(kv0 + 64) * D_;
      ushort_t* dst = &Ks[(ti + 1) & 1][0];
#pragma unroll
      for (int i = 0; i < 4; i++) {
        int row = i * 16 + st_row;
        async16(Kn + (size_t)row * D_ + (((st_slot - row) & 15) * 8),
                dst + row * 128 + st_slot * 8);
      }
    }
    const ushort_t* Kl = &Ks[ti & 1][0];
    // V half 0 — early issue, hidden under QK
    const ushort_t* Vt0 = Vfb + (size_t)(ti * 2) * 4096;
    short8 vr0[8];
#pragma unroll
    for (int n = 0; n < 8; n++)
      vr0[n] = *(const short8*)(Vt0 + n * 512 + lane * 8);
    // QK^T swapped: s[kj] lane layout: q = q0w+lr (col), k = kv0+kj*16+lc*4+r (row)
    f32x4 s[4];
#pragma unroll
    for (int kj = 0; kj < 4; kj++) s[kj] = (f32x4)(0.0f);
    __builtin_amdgcn_s_setprio(1);
#pragma unroll
    for (int c = 0; c < 4; c++) {
      short8 kf[4];
#pragma unroll
      for (int kj = 0; kj < 4; kj++)
        kf[kj] = *(const short8*)(Kl + (kj * 16 + lr) * 128 + (((c * 4 + lc + lr) & 15) * 8));
#pragma unroll
      for (int kj = 0; kj < 4; kj++)
        s[kj] = mfma16(kf[kj], qf[c], s[kj]);
    }
    __builtin_amdgcn_s_setprio(0);
    // V half 1 — hidden under softmax
    const ushort_t* Vt1 = Vfb + (size_t)(ti * 2 + 1) * 4096;
    short8 vr1[8];
#pragma unroll
    for (int n = 0; n < 8; n++)
      vr1[n] = *(const short8*)(Vt1 + n * 512 + lane * 8);
    // in-register softmax (per-lane row q), all in log2 units
    float pv[16];
    float mx = -1e30f;
    if (kv0 + 63 > q0w) {
#pragma unroll
      for (int kj = 0; kj < 4; kj++)
#pragma unroll
        for (int r = 0; r < 4; r++) {
          float a = s[kj][r];
          if (kv0 + kj * 16 + lc * 4 + r > q) a = -1e30f;
          pv[kj * 4 + r] = a;
          mx = fmaxf(mx, a);
        }
    } else {
#pragma unroll
      for (int kj = 0; kj < 4; kj++)
#pragma unroll
        for (int r = 0; r < 4; r++) {
          float a = s[kj][r];
          pv[kj * 4 + r] = a;
          mx = fmaxf(mx, a);
        }
    }
    mx = fmaxf(mx, __shfl_xor(mx, 16));
    mx = fmaxf(mx, __shfl_xor(mx, 32));
    // defer-max: rescale only when some row grew > 8 (log2) => P <= 2^8
    const bool need = __any(mx > m + 8.0f);
    const float mn = need ? fmaxf(m, mx) : m;
    float rs = 0.0f;
#pragma unroll
    for (int i = 0; i < 16; i++) {
      pv[i] = exp2f(pv[i] - mn);
      rs += pv[i];
    }
    rs += __shfl_xor(rs, 16);
    rs += __shfl_xor(rs, 32);
    // pack P to bf16 A-frags (in-lane; layout matches Vf's sigma)
    unsigned Wd[8];
#pragma unroll
    for (int kj = 0; kj < 4; kj++) {
      Wd[kj * 2] = cvtpk(pv[kj * 4], pv[kj * 4 + 1]);
      Wd[kj * 2 + 1] = cvtpk(pv[kj * 4 + 2], pv[kj * 4 + 3]);
    }
    union { unsigned u[4]; short8 v; } pa0, pa1;
#pragma unroll
    for (int t = 0; t < 4; t++) { pa0.u[t] = Wd[t]; pa1.u[t] = Wd[4 + t]; }
    if (need) {
      float al = exp2f(m - mn);
      m = mn;
      l = l * al + rs;
      float alT[4];
#pragma unroll
      for (int r = 0; r < 4; r++)
        alT[r] = __shfl(al, (lane & 48) | (lc * 4 + r));
#pragma unroll
      for (int n = 0; n < 8; n++)
#pragma unroll
        for (int r = 0; r < 4; r++) o[n][r] *= alT[r];
    } else {
      l += rs;
    }
    __builtin_amdgcn_s_setprio(1);
#pragma unroll
    for (int n = 0; n < 8; n++) o[n] = mfma16(pa0.v, vr0[n], o[n]);
#pragma unroll
    for (int n = 0; n < 8; n++) o[n] = mfma16(pa1.v, vr1[n], o[n]);
    __builtin_amdgcn_s_setprio(0);
  }
  // epilogue: o rows are q = q0w + lc*4 + r; l lives at lane q = q0w + lr
  float inv = 1.0f / l;
  float invT[4];
#pragma unroll
  for (int r = 0; r < 4; r++)
    invT[r] = __shfl(inv, (lane & 48) | (lc * 4 + r));
#pragma unroll
  for (int n = 0; n < 8; n++)
#pragma unroll
    for (int r = 0; r < 4; r++) {
      int qo = q0w + lc * 4 + r;
      int d = n * 16 + lr;
      Yb[(size_t)(b * T_ + qo) * 2048 + h * 128 + d] = f2b(o[n][r] * invT[r]);
    }
}

// ---------------- launch ----------------

extern "C" void kernel_launch(void* const* d_in, const int* in_sizes, int n_in,
                              void* d_out, int out_size, void* d_ws, size_t ws_size,
                              hipStream_t stream) {
  (void)in_sizes; (void)n_in; (void)out_size; (void)ws_size;
  const float* x = (const float*)d_in[0];
  const float* wq = (const float*)d_in[1];
  const float* wkv = (const float*)d_in[2];
  const float* wproj = (const float*)d_in[3];
  const float* omega = (const float*)d_in[4];
  float* out = (float*)d_out;
  char* ws = (char*)d_ws;

  ushort_t* xb     = (ushort_t*)(ws + 0);          // 4096x2048 bf16 = 16.8MB
  ushort_t* wqkvT  = (ushort_t*)(ws + 16777216);   // [3072][2048] bf16 (wqT then wkvT)
  ushort_t* wkvT   = (ushort_t*)(ws + 25165824);   // tail of wqkvT
  ushort_t* wprojT = (ushort_t*)(ws + 29360128);   // 2048x2048 bf16
  ushort_t* QKVraw = (ushort_t*)(ws + 37748736);   // 4096x3072 bf16 = 25.2MB
  ushort_t* Qb     = (ushort_t*)(ws + 62914560);   // [b][h][t][d] bf16
  ushort_t* Kb     = (ushort_t*)(ws + 79691776);   // [b][kh][t][d] bf16
  ushort_t* Vf     = (ushort_t*)(ws + 83886080);   // V fragment-packed, 4MB
  ushort_t* Yb     = (ushort_t*)(ws + 88080384);   // 4096x2048 bf16
  float2*   tab    = (float2*)(ws + 104857600);    // 2048x64 float2 = 1MB

  convert_f32_bf16<<<8192, 256, 0, stream>>>(x, xb, 2097152);
  transpose_to_bf16<<<dim3(64, 64), dim3(32, 8), 0, stream>>>(wq, wqkvT, 2048, 2048);
  transpose_to_bf16<<<dim3(32, 64), dim3(32, 8), 0, stream>>>(wkv, wkvT, 2048, 1024);
  transpose_to_bf16<<<dim3(64, 64), dim3(32, 8), 0, stream>>>(wproj, wprojT, 2048, 2048);
  rope_tab_k<<<512, 256, 0, stream>>>(omega, tab);

  // merged QKV projection: [4096,2048] @ [3072,2048]^T -> [4096,3072]
  gemm_bt<<<dim3(24, 32), 256, 0, stream>>>(xb, wqkvT, QKVraw, 4096, 3072, 2048);

  rope_q_k<<<16384, 256, 0, stream>>>(QKVraw, tab, Qb);
  rope_k_k<<<4096, 256, 0, stream>>>(QKVraw, tab, Kb);
  v_frag_k<<<1024, 256, 0, stream>>>(QKVraw, Vf);

  attn_k<<<dim3(32, 16, 2), 256, 0, stream>>>(Qb, Kb, Vf, Yb);

  gemm_bt<<<dim3(16, 32), 256, 0, stream>>>(Yb, wprojT, out, 4096, 2048, 2048);
}

// Round 8
// 230.271 us; speedup vs baseline: 1.9715x; 1.1139x over previous
//
#include <hip/hip_runtime.h>
#include <hip/hip_bf16.h>

#define B_ 2
#define T_ 2048
#define C_ 2048
#define H_ 16
#define KH_ 4
#define D_ 128

typedef unsigned short ushort_t;
typedef __attribute__((ext_vector_type(8))) short short8;
typedef __attribute__((ext_vector_type(4))) float f32x4;

#define RSQRT_D 0.08838834764831845f
#define L2E 1.4426950408889634f
// Q pre-scale: 1/sqrt(D) * log2(e)  ->  QK^T lands in log2 units, softmax is pure exp2
#define QSCALE (0.08838834764831845f * 1.4426950408889634f)

__device__ __forceinline__ ushort_t f2b(float f) {
  union { float f; unsigned u; } v; v.f = f;
  unsigned r = v.u + 0x7fffu + ((v.u >> 16) & 1u);
  return (ushort_t)(r >> 16);
}
__device__ __forceinline__ float b2f(ushort_t u) {
  union { unsigned u; float f; } v; v.u = ((unsigned)u) << 16;
  return v.f;
}

__device__ __forceinline__ f32x4 mfma16(short8 a, short8 b, f32x4 c) {
  return __builtin_amdgcn_mfma_f32_16x16x32_bf16(a, b, c, 0, 0, 0);
}

__device__ __forceinline__ void async16(const void* g, void* l) {
  __builtin_amdgcn_global_load_lds(
      (const __attribute__((address_space(1))) void*)g,
      (__attribute__((address_space(3))) void*)l, 16, 0, 0);
}

// packed f32x2 -> bf16x2 (RTNE); dst.lo = bf16(lo), dst.hi = bf16(hi)
__device__ __forceinline__ unsigned cvtpk(float lo, float hi) {
  unsigned r;
  asm volatile("v_cvt_pk_bf16_f32 %0, %1, %2" : "=v"(r) : "v"(lo), "v"(hi));
  return r;
}

// ---------------- small prep kernels ----------------

__global__ void convert_f32_bf16(const float* __restrict__ in, ushort_t* __restrict__ out, int n4) {
  int i = blockIdx.x * blockDim.x + threadIdx.x;
  if (i >= n4) return;
  float4 v = ((const float4*)in)[i];
  ushort4 o;
  o.x = f2b(v.x); o.y = f2b(v.y); o.z = f2b(v.z); o.w = f2b(v.w);
  ((ushort4*)out)[i] = o;
}

// out[c][r] = bf16(in[r][c]);  in: R x C f32, out: C x R bf16
__global__ void transpose_to_bf16(const float* __restrict__ in, ushort_t* __restrict__ out, int R, int C) {
  __shared__ float tile[32][33];
  int c0 = blockIdx.x * 32, r0 = blockIdx.y * 32;
  int tx = threadIdx.x, ty = threadIdx.y;
#pragma unroll
  for (int i = 0; i < 4; i++) {
    int r = ty + i * 8;
    tile[r][tx] = in[(size_t)(r0 + r) * C + c0 + tx];
  }
  __syncthreads();
#pragma unroll
  for (int i = 0; i < 4; i++) {
    int r = ty + i * 8;
    out[(size_t)(c0 + r) * R + r0 + tx] = f2b(tile[tx][r]);
  }
}

// cos/sin table: tab[t*64+d] = (cos(t*omega[d]), sin(t*omega[d]))
__global__ void rope_tab_k(const float* __restrict__ omega, float2* __restrict__ tab) {
  int idx = blockIdx.x * blockDim.x + threadIdx.x;  // 2048*64
  int d = idx & 63;
  int t = idx >> 6;
  float ang = (float)t * omega[d];
  tab[idx] = make_float2(cosf(ang), sinf(ang));
}

// QKVraw [b*T+t][3072]: cols 0..2047 = q -> rope (pre-scaled by QSCALE) -> Qb [(b*16+h)*T + t][d]
__global__ void rope_q_k(const ushort_t* __restrict__ QKVraw, const float2* __restrict__ tab,
                         ushort_t* __restrict__ Qb) {
  int idx = blockIdx.x * blockDim.x + threadIdx.x;  // B*T*H*64 = 4194304
  int d = idx & 63;
  int h = (idx >> 6) & 15;
  int t = (idx >> 10) & 2047;
  int b = idx >> 21;
  size_t in_off = (size_t)(b * 2048 + t) * 3072 + h * 128 + d;
  float x1 = b2f(QKVraw[in_off]);
  float x2 = b2f(QKVraw[in_off + 64]);
  float2 cs = tab[t * 64 + d];
  size_t out_off = ((size_t)(b * 16 + h) * 2048 + t) * 128 + d;
  Qb[out_off] = f2b((x1 * cs.x - x2 * cs.y) * QSCALE);
  Qb[out_off + 64] = f2b((x1 * cs.y + x2 * cs.x) * QSCALE);
}

// QKVraw cols 2048..2559 = k -> rope -> Kb [(b*4+kh)*T + t][d]
__global__ void rope_k_k(const ushort_t* __restrict__ QKVraw, const float2* __restrict__ tab,
                         ushort_t* __restrict__ Kb) {
  int idx = blockIdx.x * blockDim.x + threadIdx.x;  // B*T*KH*64 = 1048576
  int d = idx & 63;
  int kh = (idx >> 6) & 3;
  int t = (idx >> 8) & 2047;
  int b = idx >> 19;
  size_t in_off = (size_t)(b * 2048 + t) * 3072 + 2048 + kh * 128 + d;
  float x1 = b2f(QKVraw[in_off]);
  float x2 = b2f(QKVraw[in_off + 64]);
  float2 cs = tab[t * 64 + d];
  size_t out_off = ((size_t)(b * 4 + kh) * 2048 + t) * 128 + d;
  Kb[out_off] = f2b(x1 * cs.x - x2 * cs.y);
  Kb[out_off + 64] = f2b(x1 * cs.y + x2 * cs.x);
}

// V fragment pre-pack: Vf short8 index = (((z*32+tile)*2+hv)*8+n)*64 + lane
// element j = V[b][t = tile*64 + kl][kh][d = n*16 + (lane&15)]
// kl = (hv*2 + ((j>>1)>>1))*16 + (lane>>4)*4 + 2*((j>>1)&1) + (j&1)
__global__ void v_frag_k(const ushort_t* __restrict__ QKVraw, ushort_t* __restrict__ Vf) {
  int idx = blockIdx.x * blockDim.x + threadIdx.x;  // 262144 short8 units
  int lane = idx & 63;
  int n = (idx >> 6) & 7;
  int hv = (idx >> 9) & 1;
  int tile = (idx >> 10) & 31;
  int z = idx >> 15;  // b*4+kh
  int b = z >> 2, kh = z & 3;
  int lr = lane & 15, lc = lane >> 4;
  int d = n * 16 + lr;
  union { ushort_t u[8]; short8 v; } out;
#pragma unroll
  for (int j = 0; j < 8; j++) {
    int tw = j >> 1, par = j & 1;
    int kl = (hv * 2 + (tw >> 1)) * 16 + lc * 4 + 2 * (tw & 1) + par;
    int t = tile * 64 + kl;
    out.u[j] = QKVraw[(size_t)(b * 2048 + t) * 3072 + 2560 + kh * 128 + d];
  }
  *(short8*)(Vf + (size_t)idx * 8) = out.v;
}

// ---------------- GEMM: C[M][N] = A[M][K] @ Bt[N][K]^T  (bf16 in, f32 acc) ----------------
// 2-phase dbuf with COUNTED vmcnt (T4): raw s_barrier, vmcnt(4) keeps the 4
// prefetch loads in flight across the MFMA phase; vmcnt(0) only on the peeled
// last tile. FIFO vmcnt semantics guarantee tile-t's 4 loads are done.

__device__ __forceinline__ void store_out(float* C, size_t idx, float v) { C[idx] = v; }
__device__ __forceinline__ void store_out(ushort_t* C, size_t idx, float v) { C[idx] = f2b(v); }

template <typename OUT_T>
__global__ __launch_bounds__(256) void gemm_bt(const ushort_t* __restrict__ A,
                                               const ushort_t* __restrict__ Bt,
                                               OUT_T* __restrict__ C,
                                               int M, int N, int K) {
  __shared__ __attribute__((aligned(16))) ushort_t As[2][128 * 32];
  __shared__ __attribute__((aligned(16))) ushort_t Bs[2][128 * 32];
  const int tid = threadIdx.x;
  const int lane = tid & 63;
  const int w = tid >> 6;
  const int bm = blockIdx.y, bn = blockIdx.x;
  const int lr = lane & 15, lc = lane >> 4;
  const int wr = (w >> 1) * 64, wc = (w & 1) * 64;
  const ushort_t* Ab = A + (size_t)bm * 128 * K;
  const ushort_t* Bb = Bt + (size_t)bn * 128 * K;
  const int srow = tid >> 2;
  const int scol = (tid & 3) * 8;
  f32x4 acc[4][4];
#pragma unroll
  for (int i = 0; i < 4; i++)
#pragma unroll
    for (int j = 0; j < 4; j++) acc[i][j] = (f32x4)(0.0f);

  // prologue: stage tile 0 into buf 0 (4 vmem ops per wave)
  async16(Ab + (size_t)srow * K + scol, &As[0][0] + srow * 32 + scol);
  async16(Ab + (size_t)(srow + 64) * K + scol, &As[0][0] + (srow + 64) * 32 + scol);
  async16(Bb + (size_t)srow * K + scol, &Bs[0][0] + srow * 32 + scol);
  async16(Bb + (size_t)(srow + 64) * K + scol, &Bs[0][0] + (srow + 64) * 32 + scol);

  const int nt = K >> 5;
#pragma unroll 2
  for (int t = 0; t < nt - 1; t++) {
    const int cur = t & 1;
    // issue prefetch of tile t+1 into the other buffer (4 vmem ops)
    {
      const int k1 = (t + 1) << 5;
      ushort_t* Ad = &As[cur ^ 1][0];
      ushort_t* Bd = &Bs[cur ^ 1][0];
      async16(Ab + (size_t)srow * K + k1 + scol, Ad + srow * 32 + scol);
      async16(Ab + (size_t)(srow + 64) * K + k1 + scol, Ad + (srow + 64) * 32 + scol);
      async16(Bb + (size_t)srow * K + k1 + scol, Bd + srow * 32 + scol);
      async16(Bb + (size_t)(srow + 64) * K + k1 + scol, Bd + (srow + 64) * 32 + scol);
    }
    // wait tile t's 4 loads (oldest); let t+1's 4 stay in flight
    asm volatile("s_waitcnt vmcnt(4)" ::: "memory");
    __builtin_amdgcn_s_barrier();
    __builtin_amdgcn_sched_barrier(0);
    const ushort_t* Al = &As[cur][0];
    const ushort_t* Bl = &Bs[cur][0];
    short8 af[4], bf[4];
#pragma unroll
    for (int mi = 0; mi < 4; mi++)
      af[mi] = *(const short8*)(Al + (wr + mi * 16 + lr) * 32 + lc * 8);
#pragma unroll
    for (int ni = 0; ni < 4; ni++)
      bf[ni] = *(const short8*)(Bl + (wc + ni * 16 + lr) * 32 + lc * 8);
#pragma unroll
    for (int mi = 0; mi < 4; mi++)
#pragma unroll
      for (int ni = 0; ni < 4; ni++)
        acc[mi][ni] = mfma16(af[mi], bf[ni], acc[mi][ni]);
    asm volatile("" ::: "memory");
    __builtin_amdgcn_s_barrier();  // all waves done reading buf[cur] before t+2 overwrites
    asm volatile("" ::: "memory");
  }
  // peeled last tile: drain, then compute
  {
    const int cur = (nt - 1) & 1;
    asm volatile("s_waitcnt vmcnt(0)" ::: "memory");
    __builtin_amdgcn_s_barrier();
    __builtin_amdgcn_sched_barrier(0);
    const ushort_t* Al = &As[cur][0];
    const ushort_t* Bl = &Bs[cur][0];
    short8 af[4], bf[4];
#pragma unroll
    for (int mi = 0; mi < 4; mi++)
      af[mi] = *(const short8*)(Al + (wr + mi * 16 + lr) * 32 + lc * 8);
#pragma unroll
    for (int ni = 0; ni < 4; ni++)
      bf[ni] = *(const short8*)(Bl + (wc + ni * 16 + lr) * 32 + lc * 8);
#pragma unroll
    for (int mi = 0; mi < 4; mi++)
#pragma unroll
      for (int ni = 0; ni < 4; ni++)
        acc[mi][ni] = mfma16(af[mi], bf[ni], acc[mi][ni]);
  }
#pragma unroll
  for (int mi = 0; mi < 4; mi++) {
#pragma unroll
    for (int ni = 0; ni < 4; ni++) {
      int row = bm * 128 + wr + mi * 16 + lc * 4;
      int col = bn * 128 + wc + ni * 16 + lr;
#pragma unroll
      for (int r = 0; r < 4; r++)
        store_out(C, (size_t)(row + r) * N + col, acc[mi][ni][r]);
    }
  }
}

// ---------------- flash attention (causal GQA) ----------------
// 256 threads = 4 waves; wave w owns 16 q-rows (q0w = qc*64 + w*16).
// 1024 blocks, one 64-row chunk each, ALL co-resident (4/CU: LDS 32KB, VGPR ~84).
// COMPLEMENTARY CHUNK MAP: co-resident blocks alias mod 256 => pairs (gy, gy+8)
// share a CU; map qc = (gy&8) ? 31-((gx+gy-8)&31) : (gx+gy)&31 gives each pair
// weight (s+1)+(32-s) = 33 => EXACTLY 66 tile-units per CU. (R7's qc=31-gx
// stacked 4 equal-weight blocks per CU: makespan 128 vs 66 -> 112us.)
// Swapped QK^T (mfma(K,Q)): lane holds S row q = q0w+lr, k = kv0+kj*16+lc*4+r.
// Q pre-scaled by QSCALE (=1/sqrt(D)*log2e) -> softmax is pure exp2.
// Defer-max (thr 8 log2-units => P<=2^8). K staged in LDS (KVBLK=64, dbuf).
__global__ __launch_bounds__(256, 2) void attn_k(const ushort_t* __restrict__ Qb,
                                                 const ushort_t* __restrict__ Kb,
                                                 const ushort_t* __restrict__ Vf,
                                                 ushort_t* __restrict__ Yb) {
  __shared__ __attribute__((aligned(16))) ushort_t Ks[2][64 * 128];  // 32 KB
  const int tid = threadIdx.x;
  const int lane = tid & 63;
  const int w = tid >> 6;
  const int lr = lane & 15, lc = lane >> 4;
  const int gy = blockIdx.y;
  const int h = gy;
  const int b = blockIdx.z;
  const int kh = h >> 2;
  const int qc = (gy & 8) ? (31 - ((blockIdx.x + gy - 8) & 31))
                          : ((blockIdx.x + gy) & 31);
  const int q0w = qc * 64 + w * 16;
  const int q = q0w + lr;           // this lane's q-row

  const ushort_t* Qp = Qb + (size_t)(b * 16 + h) * T_ * D_;
  const ushort_t* Kp = Kb + (size_t)(b * 4 + kh) * T_ * D_;
  const ushort_t* Vfb = Vf + (size_t)(b * 4 + kh) * 262144;

  const int st_row = tid >> 4;   // 0..15, +i*16
  const int st_slot = tid & 15;

  short8 qf[4];
#pragma unroll
  for (int c = 0; c < 4; c++)
    qf[c] = *(const short8*)(Qp + (size_t)(q0w + lr) * D_ + c * 32 + lc * 8);

  f32x4 o[8];
#pragma unroll
  for (int n = 0; n < 8; n++) o[n] = (f32x4)(0.0f);
  float m = -1e30f, l = 0.0f;

  const int nt = qc + 1;

  // stage tile 0 into buffer 0
#pragma unroll
  for (int i = 0; i < 4; i++) {
    int row = i * 16 + st_row;
    async16(Kp + (size_t)row * D_ + (((st_slot - row) & 15) * 8),
            &Ks[0][0] + row * 128 + st_slot * 8);
  }

#pragma unroll 1
  for (int ti = 0; ti < nt; ti++) {
    __syncthreads();  // K[ti] resident (vmcnt drained); buffers safe
    const int kv0 = ti * 64;
    if (ti + 1 < nt) {
      const ushort_t* Kn = Kp + (size_t)(kv0 + 64) * D_;
      ushort_t* dst = &Ks[(ti + 1) & 1][0];
#pragma unroll
      for (int i = 0; i < 4; i++) {
        int row = i * 16 + st_row;
        async16(Kn + (size_t)row * D_ + (((st_slot - row) & 15) * 8),
                dst + row * 128 + st_slot * 8);
      }
    }
    const ushort_t* Kl = &Ks[ti & 1][0];
    // V half 0 — early issue, hidden under QK
    const ushort_t* Vt0 = Vfb + (size_t)(ti * 2) * 4096;
    short8 vr0[8];
#pragma unroll
    for (int n = 0; n < 8; n++)
      vr0[n] = *(const short8*)(Vt0 + n * 512 + lane * 8);
    // QK^T swapped: s[kj] lane layout: q = q0w+lr (col), k = kv0+kj*16+lc*4+r (row)
    f32x4 s[4];
#pragma unroll
    for (int kj = 0; kj < 4; kj++) s[kj] = (f32x4)(0.0f);
    __builtin_amdgcn_s_setprio(1);
#pragma unroll
    for (int c = 0; c < 4; c++) {
      short8 kf[4];
#pragma unroll
      for (int kj = 0; kj < 4; kj++)
        kf[kj] = *(const short8*)(Kl + (kj * 16 + lr) * 128 + (((c * 4 + lc + lr) & 15) * 8));
#pragma unroll
      for (int kj = 0; kj < 4; kj++)
        s[kj] = mfma16(kf[kj], qf[c], s[kj]);
    }
    __builtin_amdgcn_s_setprio(0);
    // V half 1 — hidden under softmax
    const ushort_t* Vt1 = Vfb + (size_t)(ti * 2 + 1) * 4096;
    short8 vr1[8];
#pragma unroll
    for (int n = 0; n < 8; n++)
      vr1[n] = *(const short8*)(Vt1 + n * 512 + lane * 8);
    // in-register softmax (per-lane row q), all in log2 units
    float pv[16];
    float mx = -1e30f;
    if (kv0 + 63 > q0w) {
#pragma unroll
      for (int kj = 0; kj < 4; kj++)
#pragma unroll
        for (int r = 0; r < 4; r++) {
          float a = s[kj][r];
          if (kv0 + kj * 16 + lc * 4 + r > q) a = -1e30f;
          pv[kj * 4 + r] = a;
          mx = fmaxf(mx, a);
        }
    } else {
#pragma unroll
      for (int kj = 0; kj < 4; kj++)
#pragma unroll
        for (int r = 0; r < 4; r++) {
          float a = s[kj][r];
          pv[kj * 4 + r] = a;
          mx = fmaxf(mx, a);
        }
    }
    mx = fmaxf(mx, __shfl_xor(mx, 16));
    mx = fmaxf(mx, __shfl_xor(mx, 32));
    // defer-max: rescale only when some row grew > 8 (log2) => P <= 2^8
    const bool need = __any(mx > m + 8.0f);
    const float mn = need ? fmaxf(m, mx) : m;
    float rs = 0.0f;
#pragma unroll
    for (int i = 0; i < 16; i++) {
      pv[i] = exp2f(pv[i] - mn);
      rs += pv[i];
    }
    rs += __shfl_xor(rs, 16);
    rs += __shfl_xor(rs, 32);
    // pack P to bf16 A-frags (in-lane; layout matches Vf's sigma)
    unsigned Wd[8];
#pragma unroll
    for (int kj = 0; kj < 4; kj++) {
      Wd[kj * 2] = cvtpk(pv[kj * 4], pv[kj * 4 + 1]);
      Wd[kj * 2 + 1] = cvtpk(pv[kj * 4 + 2], pv[kj * 4 + 3]);
    }
    union { unsigned u[4]; short8 v; } pa0, pa1;
#pragma unroll
    for (int t = 0; t < 4; t++) { pa0.u[t] = Wd[t]; pa1.u[t] = Wd[4 + t]; }
    if (need) {
      float al = exp2f(m - mn);
      m = mn;
      l = l * al + rs;
      float alT[4];
#pragma unroll
      for (int r = 0; r < 4; r++)
        alT[r] = __shfl(al, (lane & 48) | (lc * 4 + r));
#pragma unroll
      for (int n = 0; n < 8; n++)
#pragma unroll
        for (int r = 0; r < 4; r++) o[n][r] *= alT[r];
    } else {
      l += rs;
    }
    __builtin_amdgcn_s_setprio(1);
#pragma unroll
    for (int n = 0; n < 8; n++) o[n] = mfma16(pa0.v, vr0[n], o[n]);
#pragma unroll
    for (int n = 0; n < 8; n++) o[n] = mfma16(pa1.v, vr1[n], o[n]);
    __builtin_amdgcn_s_setprio(0);
  }
  // epilogue: o rows are q = q0w + lc*4 + r; l lives at lane q = q0w + lr
  float inv = 1.0f / l;
  float invT[4];
#pragma unroll
  for (int r = 0; r < 4; r++)
    invT[r] = __shfl(inv, (lane & 48) | (lc * 4 + r));
#pragma unroll
  for (int n = 0; n < 8; n++)
#pragma unroll
    for (int r = 0; r < 4; r++) {
      int qo = q0w + lc * 4 + r;
      int d = n * 16 + lr;
      Yb[(size_t)(b * T_ + qo) * 2048 + h * 128 + d] = f2b(o[n][r] * invT[r]);
    }
}

// ---------------- launch ----------------

extern "C" void kernel_launch(void* const* d_in, const int* in_sizes, int n_in,
                              void* d_out, int out_size, void* d_ws, size_t ws_size,
                              hipStream_t stream) {
  (void)in_sizes; (void)n_in; (void)out_size; (void)ws_size;
  const float* x = (const float*)d_in[0];
  const float* wq = (const float*)d_in[1];
  const float* wkv = (const float*)d_in[2];
  const float* wproj = (const float*)d_in[3];
  const float* omega = (const float*)d_in[4];
  float* out = (float*)d_out;
  char* ws = (char*)d_ws;

  ushort_t* xb     = (ushort_t*)(ws + 0);          // 4096x2048 bf16 = 16.8MB
  ushort_t* wqkvT  = (ushort_t*)(ws + 16777216);   // [3072][2048] bf16 (wqT then wkvT)
  ushort_t* wkvT   = (ushort_t*)(ws + 25165824);   // tail of wqkvT
  ushort_t* wprojT = (ushort_t*)(ws + 29360128);   // 2048x2048 bf16
  ushort_t* QKVraw = (ushort_t*)(ws + 37748736);   // 4096x3072 bf16 = 25.2MB
  ushort_t* Qb     = (ushort_t*)(ws + 62914560);   // [b][h][t][d] bf16
  ushort_t* Kb     = (ushort_t*)(ws + 79691776);   // [b][kh][t][d] bf16
  ushort_t* Vf     = (ushort_t*)(ws + 83886080);   // V fragment-packed, 4MB
  ushort_t* Yb     = (ushort_t*)(ws + 88080384);   // 4096x2048 bf16
  float2*   tab    = (float2*)(ws + 104857600);    // 2048x64 float2 = 1MB

  convert_f32_bf16<<<8192, 256, 0, stream>>>(x, xb, 2097152);
  transpose_to_bf16<<<dim3(64, 64), dim3(32, 8), 0, stream>>>(wq, wqkvT, 2048, 2048);
  transpose_to_bf16<<<dim3(32, 64), dim3(32, 8), 0, stream>>>(wkv, wkvT, 2048, 1024);
  transpose_to_bf16<<<dim3(64, 64), dim3(32, 8), 0, stream>>>(wproj, wprojT, 2048, 2048);
  rope_tab_k<<<512, 256, 0, stream>>>(omega, tab);

  // merged QKV projection: [4096,2048] @ [3072,2048]^T -> [4096,3072]
  gemm_bt<<<dim3(24, 32), 256, 0, stream>>>(xb, wqkvT, QKVraw, 4096, 3072, 2048);

  rope_q_k<<<16384, 256, 0, stream>>>(QKVraw, tab, Qb);
  rope_k_k<<<4096, 256, 0, stream>>>(QKVraw, tab, Kb);
  v_frag_k<<<1024, 256, 0, stream>>>(QKVraw, Vf);

  attn_k<<<dim3(32, 16, 2), 256, 0, stream>>>(Qb, Kb, Vf, Yb);

  gemm_bt<<<dim3(16, 32), 256, 0, stream>>>(Yb, wprojT, out, 4096, 2048, 2048);
}

// Round 9
// 221.045 us; speedup vs baseline: 2.0538x; 1.0417x over previous
//
#include <hip/hip_runtime.h>
#include <hip/hip_bf16.h>

#define B_ 2
#define T_ 2048
#define C_ 2048
#define H_ 16
#define KH_ 4
#define D_ 128

typedef unsigned short ushort_t;
typedef __attribute__((ext_vector_type(8))) short short8;
typedef __attribute__((ext_vector_type(4))) float f32x4;

#define RSQRT_D 0.08838834764831845f
#define L2E 1.4426950408889634f
// Q pre-scale: 1/sqrt(D) * log2(e)  ->  QK^T lands in log2 units, softmax is pure exp2
#define QSCALE (0.08838834764831845f * 1.4426950408889634f)

__device__ __forceinline__ ushort_t f2b(float f) {
  union { float f; unsigned u; } v; v.f = f;
  unsigned r = v.u + 0x7fffu + ((v.u >> 16) & 1u);
  return (ushort_t)(r >> 16);
}
__device__ __forceinline__ float b2f(ushort_t u) {
  union { unsigned u; float f; } v; v.u = ((unsigned)u) << 16;
  return v.f;
}

__device__ __forceinline__ f32x4 mfma16(short8 a, short8 b, f32x4 c) {
  return __builtin_amdgcn_mfma_f32_16x16x32_bf16(a, b, c, 0, 0, 0);
}

__device__ __forceinline__ void async16(const void* g, void* l) {
  __builtin_amdgcn_global_load_lds(
      (const __attribute__((address_space(1))) void*)g,
      (__attribute__((address_space(3))) void*)l, 16, 0, 0);
}

// packed f32x2 -> bf16x2 (RTNE); dst.lo = bf16(lo), dst.hi = bf16(hi)
__device__ __forceinline__ unsigned cvtpk(float lo, float hi) {
  unsigned r;
  asm volatile("v_cvt_pk_bf16_f32 %0, %1, %2" : "=v"(r) : "v"(lo), "v"(hi));
  return r;
}

// ---------------- small prep kernels ----------------

__global__ void convert_f32_bf16(const float* __restrict__ in, ushort_t* __restrict__ out, int n4) {
  int i = blockIdx.x * blockDim.x + threadIdx.x;
  if (i >= n4) return;
  float4 v = ((const float4*)in)[i];
  ushort4 o;
  o.x = f2b(v.x); o.y = f2b(v.y); o.z = f2b(v.z); o.w = f2b(v.w);
  ((ushort4*)out)[i] = o;
}

// out[c][r] = bf16(in[r][c]);  in: R x C f32, out: C x R bf16
__global__ void transpose_to_bf16(const float* __restrict__ in, ushort_t* __restrict__ out, int R, int C) {
  __shared__ float tile[32][33];
  int c0 = blockIdx.x * 32, r0 = blockIdx.y * 32;
  int tx = threadIdx.x, ty = threadIdx.y;
#pragma unroll
  for (int i = 0; i < 4; i++) {
    int r = ty + i * 8;
    tile[r][tx] = in[(size_t)(r0 + r) * C + c0 + tx];
  }
  __syncthreads();
#pragma unroll
  for (int i = 0; i < 4; i++) {
    int r = ty + i * 8;
    out[(size_t)(c0 + r) * R + r0 + tx] = f2b(tile[tx][r]);
  }
}

// cos/sin table: tab[t*64+d] = (cos(t*omega[d]), sin(t*omega[d]))
__global__ void rope_tab_k(const float* __restrict__ omega, float2* __restrict__ tab) {
  int idx = blockIdx.x * blockDim.x + threadIdx.x;  // 2048*64
  int d = idx & 63;
  int t = idx >> 6;
  float ang = (float)t * omega[d];
  tab[idx] = make_float2(cosf(ang), sinf(ang));
}

// QKVraw [b*T+t][3072]: cols 0..2047 = q -> rope (pre-scaled by QSCALE) -> Qb [(b*16+h)*T + t][d]
__global__ void rope_q_k(const ushort_t* __restrict__ QKVraw, const float2* __restrict__ tab,
                         ushort_t* __restrict__ Qb) {
  int idx = blockIdx.x * blockDim.x + threadIdx.x;  // B*T*H*64 = 4194304
  int d = idx & 63;
  int h = (idx >> 6) & 15;
  int t = (idx >> 10) & 2047;
  int b = idx >> 21;
  size_t in_off = (size_t)(b * 2048 + t) * 3072 + h * 128 + d;
  float x1 = b2f(QKVraw[in_off]);
  float x2 = b2f(QKVraw[in_off + 64]);
  float2 cs = tab[t * 64 + d];
  size_t out_off = ((size_t)(b * 16 + h) * 2048 + t) * 128 + d;
  Qb[out_off] = f2b((x1 * cs.x - x2 * cs.y) * QSCALE);
  Qb[out_off + 64] = f2b((x1 * cs.y + x2 * cs.x) * QSCALE);
}

// QKVraw cols 2048..2559 = k -> rope -> Kb [(b*4+kh)*T + t][d]
__global__ void rope_k_k(const ushort_t* __restrict__ QKVraw, const float2* __restrict__ tab,
                         ushort_t* __restrict__ Kb) {
  int idx = blockIdx.x * blockDim.x + threadIdx.x;  // B*T*KH*64 = 1048576
  int d = idx & 63;
  int kh = (idx >> 6) & 3;
  int t = (idx >> 8) & 2047;
  int b = idx >> 19;
  size_t in_off = (size_t)(b * 2048 + t) * 3072 + 2048 + kh * 128 + d;
  float x1 = b2f(QKVraw[in_off]);
  float x2 = b2f(QKVraw[in_off + 64]);
  float2 cs = tab[t * 64 + d];
  size_t out_off = ((size_t)(b * 4 + kh) * 2048 + t) * 128 + d;
  Kb[out_off] = f2b(x1 * cs.x - x2 * cs.y);
  Kb[out_off + 64] = f2b(x1 * cs.y + x2 * cs.x);
}

// V fragment pre-pack: Vf short8 index = (((z*32+tile)*2+hv)*8+n)*64 + lane
// element j = V[b][t = tile*64 + kl][kh][d = n*16 + (lane&15)]
// kl = (hv*2 + ((j>>1)>>1))*16 + (lane>>4)*4 + 2*((j>>1)&1) + (j&1)
__global__ void v_frag_k(const ushort_t* __restrict__ QKVraw, ushort_t* __restrict__ Vf) {
  int idx = blockIdx.x * blockDim.x + threadIdx.x;  // 262144 short8 units
  int lane = idx & 63;
  int n = (idx >> 6) & 7;
  int hv = (idx >> 9) & 1;
  int tile = (idx >> 10) & 31;
  int z = idx >> 15;  // b*4+kh
  int b = z >> 2, kh = z & 3;
  int lr = lane & 15, lc = lane >> 4;
  int d = n * 16 + lr;
  union { ushort_t u[8]; short8 v; } out;
#pragma unroll
  for (int j = 0; j < 8; j++) {
    int tw = j >> 1, par = j & 1;
    int kl = (hv * 2 + (tw >> 1)) * 16 + lc * 4 + 2 * (tw & 1) + par;
    int t = tile * 64 + kl;
    out.u[j] = QKVraw[(size_t)(b * 2048 + t) * 3072 + 2560 + kh * 128 + d];
  }
  *(short8*)(Vf + (size_t)idx * 8) = out.v;
}

// ---------------- GEMM: C[M][N] = A[M][K] @ Bt[N][K]^T  (bf16 in, f32 acc) ----------------
// 2-phase dbuf with COUNTED vmcnt (T4): raw s_barrier, vmcnt(4) keeps the 4
// prefetch loads in flight across the MFMA phase; vmcnt(0) only on the peeled
// last tile. FIFO vmcnt semantics guarantee tile-t's 4 loads are done.

__device__ __forceinline__ void store_out(float* C, size_t idx, float v) { C[idx] = v; }
__device__ __forceinline__ void store_out(ushort_t* C, size_t idx, float v) { C[idx] = f2b(v); }

template <typename OUT_T>
__global__ __launch_bounds__(256) void gemm_bt(const ushort_t* __restrict__ A,
                                               const ushort_t* __restrict__ Bt,
                                               OUT_T* __restrict__ C,
                                               int M, int N, int K) {
  __shared__ __attribute__((aligned(16))) ushort_t As[2][128 * 32];
  __shared__ __attribute__((aligned(16))) ushort_t Bs[2][128 * 32];
  const int tid = threadIdx.x;
  const int lane = tid & 63;
  const int w = tid >> 6;
  const int bm = blockIdx.y, bn = blockIdx.x;
  const int lr = lane & 15, lc = lane >> 4;
  const int wr = (w >> 1) * 64, wc = (w & 1) * 64;
  const ushort_t* Ab = A + (size_t)bm * 128 * K;
  const ushort_t* Bb = Bt + (size_t)bn * 128 * K;
  const int srow = tid >> 2;
  const int scol = (tid & 3) * 8;
  f32x4 acc[4][4];
#pragma unroll
  for (int i = 0; i < 4; i++)
#pragma unroll
    for (int j = 0; j < 4; j++) acc[i][j] = (f32x4)(0.0f);

  // prologue: stage tile 0 into buf 0 (4 vmem ops per wave)
  async16(Ab + (size_t)srow * K + scol, &As[0][0] + srow * 32 + scol);
  async16(Ab + (size_t)(srow + 64) * K + scol, &As[0][0] + (srow + 64) * 32 + scol);
  async16(Bb + (size_t)srow * K + scol, &Bs[0][0] + srow * 32 + scol);
  async16(Bb + (size_t)(srow + 64) * K + scol, &Bs[0][0] + (srow + 64) * 32 + scol);

  const int nt = K >> 5;
#pragma unroll 2
  for (int t = 0; t < nt - 1; t++) {
    const int cur = t & 1;
    // issue prefetch of tile t+1 into the other buffer (4 vmem ops)
    {
      const int k1 = (t + 1) << 5;
      ushort_t* Ad = &As[cur ^ 1][0];
      ushort_t* Bd = &Bs[cur ^ 1][0];
      async16(Ab + (size_t)srow * K + k1 + scol, Ad + srow * 32 + scol);
      async16(Ab + (size_t)(srow + 64) * K + k1 + scol, Ad + (srow + 64) * 32 + scol);
      async16(Bb + (size_t)srow * K + k1 + scol, Bd + srow * 32 + scol);
      async16(Bb + (size_t)(srow + 64) * K + k1 + scol, Bd + (srow + 64) * 32 + scol);
    }
    // wait tile t's 4 loads (oldest); let t+1's 4 stay in flight
    asm volatile("s_waitcnt vmcnt(4)" ::: "memory");
    __builtin_amdgcn_s_barrier();
    __builtin_amdgcn_sched_barrier(0);
    const ushort_t* Al = &As[cur][0];
    const ushort_t* Bl = &Bs[cur][0];
    short8 af[4], bf[4];
#pragma unroll
    for (int mi = 0; mi < 4; mi++)
      af[mi] = *(const short8*)(Al + (wr + mi * 16 + lr) * 32 + lc * 8);
#pragma unroll
    for (int ni = 0; ni < 4; ni++)
      bf[ni] = *(const short8*)(Bl + (wc + ni * 16 + lr) * 32 + lc * 8);
#pragma unroll
    for (int mi = 0; mi < 4; mi++)
#pragma unroll
      for (int ni = 0; ni < 4; ni++)
        acc[mi][ni] = mfma16(af[mi], bf[ni], acc[mi][ni]);
    asm volatile("" ::: "memory");
    __builtin_amdgcn_s_barrier();  // all waves done reading buf[cur] before t+2 overwrites
    asm volatile("" ::: "memory");
  }
  // peeled last tile: drain, then compute
  {
    const int cur = (nt - 1) & 1;
    asm volatile("s_waitcnt vmcnt(0)" ::: "memory");
    __builtin_amdgcn_s_barrier();
    __builtin_amdgcn_sched_barrier(0);
    const ushort_t* Al = &As[cur][0];
    const ushort_t* Bl = &Bs[cur][0];
    short8 af[4], bf[4];
#pragma unroll
    for (int mi = 0; mi < 4; mi++)
      af[mi] = *(const short8*)(Al + (wr + mi * 16 + lr) * 32 + lc * 8);
#pragma unroll
    for (int ni = 0; ni < 4; ni++)
      bf[ni] = *(const short8*)(Bl + (wc + ni * 16 + lr) * 32 + lc * 8);
#pragma unroll
    for (int mi = 0; mi < 4; mi++)
#pragma unroll
      for (int ni = 0; ni < 4; ni++)
        acc[mi][ni] = mfma16(af[mi], bf[ni], acc[mi][ni]);
  }
#pragma unroll
  for (int mi = 0; mi < 4; mi++) {
#pragma unroll
    for (int ni = 0; ni < 4; ni++) {
      int row = bm * 128 + wr + mi * 16 + lc * 4;
      int col = bn * 128 + wc + ni * 16 + lr;
#pragma unroll
      for (int r = 0; r < 4; r++)
        store_out(C, (size_t)(row + r) * N + col, acc[mi][ni][r]);
    }
  }
}

// ---------------- flash attention (causal GQA) ----------------
// QBLK=128: 256 threads = 4 waves, each wave owns 32 q-rows as TWO 16-row
// fragments (q0w = qc*128 + w*32; frag f rows q0w+f*16..+15). The 16 K-frag
// ds_reads per tile now feed 64 MFMAs (was 32) -> LDS read traffic per FLOP
// HALVED (it was the largest pipe: ~42us of ds_read_b128 vs 17us MFMA floor).
// 512 blocks; co-resident pair (same gx,gy, b=0/1) gets complementary chunks
// (s, 15-s) -> exactly 34 tile-units per CU.
// Swapped QK^T (mfma(K,Q)): lane holds S row q = q0w+f*16+lr, k = kv0+kj*16+lc*4+r.
// Q pre-scaled by QSCALE -> softmax pure exp2; defer-max thr 8 (P<=2^8).
__global__ __launch_bounds__(256, 2) void attn_k(const ushort_t* __restrict__ Qb,
                                                 const ushort_t* __restrict__ Kb,
                                                 const ushort_t* __restrict__ Vf,
                                                 ushort_t* __restrict__ Yb) {
  __shared__ __attribute__((aligned(16))) ushort_t Ks[2][64 * 128];  // 32 KB
  const int tid = threadIdx.x;
  const int lane = tid & 63;
  const int w = tid >> 6;
  const int lr = lane & 15, lc = lane >> 4;
  const int gy = blockIdx.y;
  const int h = gy;
  const int b = blockIdx.z;
  const int kh = h >> 2;
  // complementary chunk map: b=0 gets s=(gx+gy)&15, b=1 gets 15-s (same CU)
  const int qc = b ? (15 - ((blockIdx.x + gy) & 15)) : ((blockIdx.x + gy) & 15);
  const int q0w = qc * 128 + w * 32;

  const ushort_t* Qp = Qb + (size_t)(b * 16 + h) * T_ * D_;
  const ushort_t* Kp = Kb + (size_t)(b * 4 + kh) * T_ * D_;
  const ushort_t* Vfb = Vf + (size_t)(b * 4 + kh) * 262144;

  const int st_row = tid >> 4;   // 0..15, +i*16
  const int st_slot = tid & 15;

  short8 qf[2][4];
#pragma unroll
  for (int f = 0; f < 2; f++)
#pragma unroll
    for (int c = 0; c < 4; c++)
      qf[f][c] = *(const short8*)(Qp + (size_t)(q0w + f * 16 + lr) * D_ + c * 32 + lc * 8);

  f32x4 o[2][8];
#pragma unroll
  for (int f = 0; f < 2; f++)
#pragma unroll
    for (int n = 0; n < 8; n++) o[f][n] = (f32x4)(0.0f);
  float m[2] = {-1e30f, -1e30f}, l[2] = {0.0f, 0.0f};

  const int nt = 2 * qc + 2;  // kv tiles of 64 covering rows qc*128..+127

  // stage tile 0 into buffer 0
#pragma unroll
  for (int i = 0; i < 4; i++) {
    int row = i * 16 + st_row;
    async16(Kp + (size_t)row * D_ + (((st_slot - row) & 15) * 8),
            &Ks[0][0] + row * 128 + st_slot * 8);
  }

#pragma unroll 1
  for (int ti = 0; ti < nt; ti++) {
    __syncthreads();  // K[ti] resident (vmcnt drained); buffers safe
    const int kv0 = ti * 64;
    if (ti + 1 < nt) {
      const ushort_t* Kn = Kp + (size_t)(kv0 + 64) * D_;
      ushort_t* dst = &Ks[(ti + 1) & 1][0];
#pragma unroll
      for (int i = 0; i < 4; i++) {
        int row = i * 16 + st_row;
        async16(Kn + (size_t)row * D_ + (((st_slot - row) & 15) * 8),
                dst + row * 128 + st_slot * 8);
      }
    }
    if (kv0 > q0w + 31) continue;  // wave fully masked (only last tile, waves 0-1)
    const ushort_t* Kl = &Ks[ti & 1][0];
    // V half 0 — early issue, hidden under QK
    const ushort_t* Vt0 = Vfb + (size_t)(ti * 2) * 4096;
    short8 vr0[8];
#pragma unroll
    for (int n = 0; n < 8; n++)
      vr0[n] = *(const short8*)(Vt0 + n * 512 + lane * 8);
    // QK^T swapped, both fragments off the SAME kf reads (the whole point)
    f32x4 s[2][4];
#pragma unroll
    for (int f = 0; f < 2; f++)
#pragma unroll
      for (int kj = 0; kj < 4; kj++) s[f][kj] = (f32x4)(0.0f);
    __builtin_amdgcn_s_setprio(1);
#pragma unroll
    for (int c = 0; c < 4; c++) {
      short8 kf[4];
#pragma unroll
      for (int kj = 0; kj < 4; kj++)
        kf[kj] = *(const short8*)(Kl + (kj * 16 + lr) * 128 + (((c * 4 + lc + lr) & 15) * 8));
#pragma unroll
      for (int f = 0; f < 2; f++)
#pragma unroll
        for (int kj = 0; kj < 4; kj++)
          s[f][kj] = mfma16(kf[kj], qf[f][c], s[f][kj]);
    }
    __builtin_amdgcn_s_setprio(0);
    // V half 1 — hidden under softmax
    const ushort_t* Vt1 = Vfb + (size_t)(ti * 2 + 1) * 4096;
    short8 vr1[8];
#pragma unroll
    for (int n = 0; n < 8; n++)
      vr1[n] = *(const short8*)(Vt1 + n * 512 + lane * 8);
    // softmax per fragment (lane's row q = q0w + f*16 + lr), log2 units
    const bool maskt = (kv0 + 63 > q0w);
    union { unsigned u[4]; short8 v; } pa0[2], pa1[2];
#pragma unroll
    for (int f = 0; f < 2; f++) {
      const int q = q0w + f * 16 + lr;
      float pv[16];
      float mx = -1e30f;
      if (maskt) {
#pragma unroll
        for (int kj = 0; kj < 4; kj++)
#pragma unroll
          for (int r = 0; r < 4; r++) {
            float a = s[f][kj][r];
            if (kv0 + kj * 16 + lc * 4 + r > q) a = -1e30f;
            pv[kj * 4 + r] = a;
            mx = fmaxf(mx, a);
          }
      } else {
#pragma unroll
        for (int kj = 0; kj < 4; kj++)
#pragma unroll
          for (int r = 0; r < 4; r++) {
            float a = s[f][kj][r];
            pv[kj * 4 + r] = a;
            mx = fmaxf(mx, a);
          }
      }
      mx = fmaxf(mx, __shfl_xor(mx, 16));
      mx = fmaxf(mx, __shfl_xor(mx, 32));
      // defer-max: rescale only when some row grew > 8 (log2) => P <= 2^8
      const bool need = __any(mx > m[f] + 8.0f);
      const float mn = need ? fmaxf(m[f], mx) : m[f];
      float rs = 0.0f;
#pragma unroll
      for (int i = 0; i < 16; i++) {
        pv[i] = exp2f(pv[i] - mn);
        rs += pv[i];
      }
      rs += __shfl_xor(rs, 16);
      rs += __shfl_xor(rs, 32);
      // pack P to bf16 A-frags (in-lane; layout matches Vf's sigma)
#pragma unroll
      for (int kj = 0; kj < 2; kj++) {
        pa0[f].u[kj * 2] = cvtpk(pv[kj * 4], pv[kj * 4 + 1]);
        pa0[f].u[kj * 2 + 1] = cvtpk(pv[kj * 4 + 2], pv[kj * 4 + 3]);
        pa1[f].u[kj * 2] = cvtpk(pv[8 + kj * 4], pv[8 + kj * 4 + 1]);
        pa1[f].u[kj * 2 + 1] = cvtpk(pv[8 + kj * 4 + 2], pv[8 + kj * 4 + 3]);
      }
      if (need) {
        float al = exp2f(m[f] - mn);
        m[f] = mn;
        l[f] = l[f] * al + rs;
        float alT[4];
#pragma unroll
        for (int r = 0; r < 4; r++)
          alT[r] = __shfl(al, (lane & 48) | (lc * 4 + r));
#pragma unroll
        for (int n = 0; n < 8; n++)
#pragma unroll
          for (int r = 0; r < 4; r++) o[f][n][r] *= alT[r];
      } else {
        l[f] += rs;
      }
    }
    __builtin_amdgcn_s_setprio(1);
#pragma unroll
    for (int n = 0; n < 8; n++) {
      o[0][n] = mfma16(pa0[0].v, vr0[n], o[0][n]);
      o[1][n] = mfma16(pa0[1].v, vr0[n], o[1][n]);
    }
#pragma unroll
    for (int n = 0; n < 8; n++) {
      o[0][n] = mfma16(pa1[0].v, vr1[n], o[0][n]);
      o[1][n] = mfma16(pa1[1].v, vr1[n], o[1][n]);
    }
    __builtin_amdgcn_s_setprio(0);
  }
  // epilogue: o[f] rows are q = q0w + f*16 + lc*4 + r; l[f] lives at lane q0w+f*16+lr
#pragma unroll
  for (int f = 0; f < 2; f++) {
    float inv = 1.0f / l[f];
    float invT[4];
#pragma unroll
    for (int r = 0; r < 4; r++)
      invT[r] = __shfl(inv, (lane & 48) | (lc * 4 + r));
#pragma unroll
    for (int n = 0; n < 8; n++)
#pragma unroll
      for (int r = 0; r < 4; r++) {
        int qo = q0w + f * 16 + lc * 4 + r;
        int d = n * 16 + lr;
        Yb[(size_t)(b * T_ + qo) * 2048 + h * 128 + d] = f2b(o[f][n][r] * invT[r]);
      }
  }
}

// ---------------- launch ----------------

extern "C" void kernel_launch(void* const* d_in, const int* in_sizes, int n_in,
                              void* d_out, int out_size, void* d_ws, size_t ws_size,
                              hipStream_t stream) {
  (void)in_sizes; (void)n_in; (void)out_size; (void)ws_size;
  const float* x = (const float*)d_in[0];
  const float* wq = (const float*)d_in[1];
  const float* wkv = (const float*)d_in[2];
  const float* wproj = (const float*)d_in[3];
  const float* omega = (const float*)d_in[4];
  float* out = (float*)d_out;
  char* ws = (char*)d_ws;

  ushort_t* xb     = (ushort_t*)(ws + 0);          // 4096x2048 bf16 = 16.8MB
  ushort_t* wqkvT  = (ushort_t*)(ws + 16777216);   // [3072][2048] bf16 (wqT then wkvT)
  ushort_t* wkvT   = (ushort_t*)(ws + 25165824);   // tail of wqkvT
  ushort_t* wprojT = (ushort_t*)(ws + 29360128);   // 2048x2048 bf16
  ushort_t* QKVraw = (ushort_t*)(ws + 37748736);   // 4096x3072 bf16 = 25.2MB
  ushort_t* Qb     = (ushort_t*)(ws + 62914560);   // [b][h][t][d] bf16
  ushort_t* Kb     = (ushort_t*)(ws + 79691776);   // [b][kh][t][d] bf16
  ushort_t* Vf     = (ushort_t*)(ws + 83886080);   // V fragment-packed, 4MB
  ushort_t* Yb     = (ushort_t*)(ws + 88080384);   // 4096x2048 bf16
  float2*   tab    = (float2*)(ws + 104857600);    // 2048x64 float2 = 1MB

  convert_f32_bf16<<<8192, 256, 0, stream>>>(x, xb, 2097152);
  transpose_to_bf16<<<dim3(64, 64), dim3(32, 8), 0, stream>>>(wq, wqkvT, 2048, 2048);
  transpose_to_bf16<<<dim3(32, 64), dim3(32, 8), 0, stream>>>(wkv, wkvT, 2048, 1024);
  transpose_to_bf16<<<dim3(64, 64), dim3(32, 8), 0, stream>>>(wproj, wprojT, 2048, 2048);
  rope_tab_k<<<512, 256, 0, stream>>>(omega, tab);

  // merged QKV projection: [4096,2048] @ [3072,2048]^T -> [4096,3072]
  gemm_bt<<<dim3(24, 32), 256, 0, stream>>>(xb, wqkvT, QKVraw, 4096, 3072, 2048);

  rope_q_k<<<16384, 256, 0, stream>>>(QKVraw, tab, Qb);
  rope_k_k<<<4096, 256, 0, stream>>>(QKVraw, tab, Kb);
  v_frag_k<<<1024, 256, 0, stream>>>(QKVraw, Vf);

  attn_k<<<dim3(16, 16, 2), 256, 0, stream>>>(Qb, Kb, Vf, Yb);

  gemm_bt<<<dim3(16, 32), 256, 0, stream>>>(Yb, wprojT, out, 4096, 2048, 2048);
}